// Round 1
// baseline (27.270 us; speedup 1.0000x reference)
//
#include <hip/hip_runtime.h>
#include <hip/hip_bf16.h>
#include <math.h>

#define LOG2E 1.4426950408889634f
#define LN2   0.6931471805599453f

__device__ __forceinline__ float fast_exp2(float x) {
#if __has_builtin(__builtin_amdgcn_exp2f)
    return __builtin_amdgcn_exp2f(x);
#else
    return exp2f(x);
#endif
}

// ---------------------------------------------------------------------------
// Prep kernel: one block of M=1024 threads. Computes per-component fused
// coefficients in the log2 domain, anchored at Lmax so that t <= 0 always.
//   t_ij = c0 + c1*x + c2*y + (-G00)*x^2 + (-G2)*x*y + (-G11)*y^2
// where G's = gamma * log2(e), c's fold mu and the log-weight.
// out4[j] = (c0 - Lmax, c1, c2, -G00);  out2[j] = (-G2, -G11); outLmax = Lmax
// ---------------------------------------------------------------------------
__global__ __launch_bounds__(1024) void gm_prep(
        const float* __restrict__ mu,   // [M,2]
        const float* __restrict__ A,    // [M,2,2]
        const float* __restrict__ w,    // [M,1]
        float4* __restrict__ out4,
        float2* __restrict__ out2,
        float*  __restrict__ outLmax) {
    __shared__ float red[16];
    const int j = threadIdx.x;          // 0..1023 == component index
    const float wj = w[j];

    // ---- block max of w (for stable logsumexp) ----
    float v = wj;
    #pragma unroll
    for (int o = 32; o; o >>= 1) v = fmaxf(v, __shfl_xor(v, o, 64));
    if ((j & 63) == 0) red[j >> 6] = v;
    __syncthreads();
    float wmax = red[0];
    #pragma unroll
    for (int k = 1; k < 16; k++) wmax = fmaxf(wmax, red[k]);
    __syncthreads();

    // ---- block sum of exp(w - wmax) ----
    float ev = expf(wj - wmax);
    v = ev;
    #pragma unroll
    for (int o = 32; o; o >>= 1) v += __shfl_xor(v, o, 64);
    if ((j & 63) == 0) red[j >> 6] = v;
    __syncthreads();
    float sumew = 0.f;
    #pragma unroll
    for (int k = 0; k < 16; k++) sumew += red[k];
    __syncthreads();
    const float lse = wmax + logf(sumew);

    // ---- gamma = A A^T / 2 and component log-weight ----
    const float a00 = A[4*j + 0], a01 = A[4*j + 1];
    const float a10 = A[4*j + 2], a11 = A[4*j + 3];
    const float g00 = 0.5f * (a00*a00 + a01*a01);
    const float g01 = 0.5f * (a00*a10 + a01*a11);
    const float g11 = 0.5f * (a10*a10 + a11*a11);
    const float det = g00*g11 - g01*g01;
    const float lw  = (wj - lse) + 0.5f * logf(det);   // natural log
    const float lw2 = lw * LOG2E;                      // log2 domain

    // ---- Lmax = max_j lw2 (since q >= 0, t_ij <= lw2_j <= Lmax) ----
    v = lw2;
    #pragma unroll
    for (int o = 32; o; o >>= 1) v = fmaxf(v, __shfl_xor(v, o, 64));
    if ((j & 63) == 0) red[j >> 6] = v;
    __syncthreads();
    float Lmax = red[0];
    #pragma unroll
    for (int k = 1; k < 16; k++) Lmax = fmaxf(Lmax, red[k]);

    // ---- fused polynomial coefficients (log2 domain) ----
    const float G00 = g00 * LOG2E;
    const float G2  = 2.f * g01 * LOG2E;
    const float G11 = g11 * LOG2E;
    const float mx = mu[2*j + 0], my = mu[2*j + 1];
    const float c1 = 2.f*G00*mx + G2*my;
    const float c2 = G2*mx + 2.f*G11*my;
    const float c0 = lw2 - (G00*mx*mx + G2*mx*my + G11*my*my) - Lmax;

    out4[j] = make_float4(c0, c1, c2, -G00);
    out2[j] = make_float2(-G2, -G11);
    if (j == 0) outLmax[0] = Lmax;
}

// ---------------------------------------------------------------------------
// Main kernel: 64 samples per block, 4 threads per sample (each covers 256
// of the 1024 components). Params staged in LDS; every lane of a wave reads
// the same LDS address per iteration -> broadcast (conflict-free).
// ---------------------------------------------------------------------------
__global__ __launch_bounds__(256) void gm_main(
        const float* __restrict__ sample,   // [N,2]
        const float4* __restrict__ gp4,
        const float2* __restrict__ gp2,
        const float* __restrict__ gLmax,
        float* __restrict__ out) {          // [N,1]
    __shared__ float4 P4[1024];
    __shared__ float2 P2[1024];
    __shared__ float SRED[256];
    __shared__ float MRED[256];

    const int tid = threadIdx.x;
    for (int k = tid; k < 1024; k += 256) { P4[k] = gp4[k]; P2[k] = gp2[k]; }
    __syncthreads();

    const int slane = tid & 63;
    const int part  = tid >> 6;            // wave-uniform
    const int i     = blockIdx.x * 64 + slane;

    const float2 xy = ((const float2*)sample)[i];
    const float x = xy.x, y = xy.y;
    const float X2 = x*x, XY = x*y, Y2 = y*y;

    float s0 = 0.f, s1 = 0.f, s2 = 0.f, s3 = 0.f;
    float m0 = -3e38f, m1 = -3e38f;
    const int jb = part << 8;

    for (int jj = 0; jj < 256; jj += 4) {
        const int j = jb + jj;
        float4 a0 = P4[j+0]; float2 b0 = P2[j+0];
        float4 a1 = P4[j+1]; float2 b1 = P2[j+1];
        float4 a2 = P4[j+2]; float2 b2 = P2[j+2];
        float4 a3 = P4[j+3]; float2 b3 = P2[j+3];

        float t0 = fmaf(a0.y, x, a0.x); t0 = fmaf(a0.z, y, t0);
        t0 = fmaf(a0.w, X2, t0); t0 = fmaf(b0.x, XY, t0); t0 = fmaf(b0.y, Y2, t0);
        float t1 = fmaf(a1.y, x, a1.x); t1 = fmaf(a1.z, y, t1);
        t1 = fmaf(a1.w, X2, t1); t1 = fmaf(b1.x, XY, t1); t1 = fmaf(b1.y, Y2, t1);
        float t2 = fmaf(a2.y, x, a2.x); t2 = fmaf(a2.z, y, t2);
        t2 = fmaf(a2.w, X2, t2); t2 = fmaf(b2.x, XY, t2); t2 = fmaf(b2.y, Y2, t2);
        float t3 = fmaf(a3.y, x, a3.x); t3 = fmaf(a3.z, y, t3);
        t3 = fmaf(a3.w, X2, t3); t3 = fmaf(b3.x, XY, t3); t3 = fmaf(b3.y, Y2, t3);

        s0 += fast_exp2(t0); m0 = fmaxf(m0, t0);
        s1 += fast_exp2(t1); m1 = fmaxf(m1, t1);
        s2 += fast_exp2(t2); m0 = fmaxf(m0, t2);
        s3 += fast_exp2(t3); m1 = fmaxf(m1, t3);
    }

    SRED[tid] = (s0 + s1) + (s2 + s3);
    MRED[tid] = fmaxf(m0, m1);
    __syncthreads();

    if (tid < 64) {
        const float Lmax = gLmax[0];
        float st = SRED[tid] + SRED[tid+64] + SRED[tid+128] + SRED[tid+192];
        float mt = fmaxf(fmaxf(MRED[tid], MRED[tid+64]),
                         fmaxf(MRED[tid+128], MRED[tid+192]));
        float ll;
        if (st >= 1e-30f) {
            ll = LN2 * (Lmax + log2f(st));
        } else {
            // Rare underflow path: re-anchor at this sample's own max.
            float s2t = 0.f;
            for (int j = 0; j < 1024; j++) {
                float4 a = P4[j]; float2 b = P2[j];
                float t = fmaf(a.y, x, a.x); t = fmaf(a.z, y, t);
                t = fmaf(a.w, X2, t); t = fmaf(b.x, XY, t); t = fmaf(b.y, Y2, t);
                s2t += fast_exp2(t - mt);
            }
            ll = LN2 * (Lmax + mt + log2f(s2t));
        }
        out[i] = ll;
    }
}

extern "C" void kernel_launch(void* const* d_in, const int* in_sizes, int n_in,
                              void* d_out, int out_size, void* d_ws, size_t ws_size,
                              hipStream_t stream) {
    const float* sample = (const float*)d_in[0];   // [N,2]
    const float* mu     = (const float*)d_in[1];   // [M,2]
    const float* A      = (const float*)d_in[2];   // [M,2,2]
    const float* w      = (const float*)d_in[3];   // [M,1]
    float* out = (float*)d_out;

    const int N = in_sizes[0] / 2;                 // 65536
    // M fixed at 1024 by the problem (LDS arrays sized statically).

    float4* p4  = (float4*)d_ws;                          // 1024 * 16 B
    float2* p2  = (float2*)((char*)d_ws + 1024 * 16);     // 1024 * 8 B
    float* lmax = (float*)((char*)d_ws + 1024 * 24);      // 4 B

    gm_prep<<<1, 1024, 0, stream>>>(mu, A, w, p4, p2, lmax);
    gm_main<<<N / 64, 256, 0, stream>>>(sample, p4, p2, lmax, out);
}

// Round 2
// 25.769 us; speedup vs baseline: 1.0583x; 1.0583x over previous
//
#include <hip/hip_runtime.h>
#include <hip/hip_bf16.h>
#include <math.h>

#define LOG2E 1.4426950408889634f
#define LN2   0.6931471805599453f

typedef float v2f __attribute__((ext_vector_type(2)));

__device__ __forceinline__ float fast_exp2(float x) {
#if __has_builtin(__builtin_amdgcn_exp2f)
    return __builtin_amdgcn_exp2f(x);
#else
    return exp2f(x);
#endif
}

// ---------------------------------------------------------------------------
// Prep kernel: one block of M=1024 threads. Computes per-component fused
// coefficients in the log2 domain, anchored at Lmax so that t <= 0 always:
//   t_ij = c0 + c1*x + c2*y + d0*x^2 + d1*x*y + d2*y^2      (d's negated G's)
// Output layout (for packed-pair consumption): for pair p = j>>1, half h=j&1:
//   gcoef[p*12 + 2*k + h] = coef_k of component j,  k in {c0,c1,c2,d0,d1,d2}
// ---------------------------------------------------------------------------
__global__ __launch_bounds__(1024) void gm_prep(
        const float* __restrict__ mu,   // [M,2]
        const float* __restrict__ A,    // [M,2,2]
        const float* __restrict__ w,    // [M,1]
        float* __restrict__ gcoef,      // [512 pairs][6][2]
        float* __restrict__ outLmax) {
    __shared__ float red[16];
    const int j = threadIdx.x;          // 0..1023 == component index
    const float wj = w[j];

    // ---- block max of w (for stable logsumexp) ----
    float v = wj;
    #pragma unroll
    for (int o = 32; o; o >>= 1) v = fmaxf(v, __shfl_xor(v, o, 64));
    if ((j & 63) == 0) red[j >> 6] = v;
    __syncthreads();
    float wmax = red[0];
    #pragma unroll
    for (int k = 1; k < 16; k++) wmax = fmaxf(wmax, red[k]);
    __syncthreads();

    // ---- block sum of exp(w - wmax) ----
    float ev = expf(wj - wmax);
    v = ev;
    #pragma unroll
    for (int o = 32; o; o >>= 1) v += __shfl_xor(v, o, 64);
    if ((j & 63) == 0) red[j >> 6] = v;
    __syncthreads();
    float sumew = 0.f;
    #pragma unroll
    for (int k = 0; k < 16; k++) sumew += red[k];
    __syncthreads();
    const float lse = wmax + logf(sumew);

    // ---- gamma = A A^T / 2 and component log-weight ----
    const float a00 = A[4*j + 0], a01 = A[4*j + 1];
    const float a10 = A[4*j + 2], a11 = A[4*j + 3];
    const float g00 = 0.5f * (a00*a00 + a01*a01);
    const float g01 = 0.5f * (a00*a10 + a01*a11);
    const float g11 = 0.5f * (a10*a10 + a11*a11);
    const float det = g00*g11 - g01*g01;
    const float lw  = (wj - lse) + 0.5f * logf(det);   // natural log
    const float lw2 = lw * LOG2E;                      // log2 domain

    // ---- Lmax = max_j lw2 (since q >= 0, t_ij <= lw2_j <= Lmax) ----
    v = lw2;
    #pragma unroll
    for (int o = 32; o; o >>= 1) v = fmaxf(v, __shfl_xor(v, o, 64));
    if ((j & 63) == 0) red[j >> 6] = v;
    __syncthreads();
    float Lmax = red[0];
    #pragma unroll
    for (int k = 1; k < 16; k++) Lmax = fmaxf(Lmax, red[k]);

    // ---- fused polynomial coefficients (log2 domain) ----
    const float G00 = g00 * LOG2E;
    const float G2  = 2.f * g01 * LOG2E;
    const float G11 = g11 * LOG2E;
    const float mx = mu[2*j + 0], my = mu[2*j + 1];
    const float c1 = 2.f*G00*mx + G2*my;
    const float c2 = G2*mx + 2.f*G11*my;
    const float c0 = lw2 - (G00*mx*mx + G2*mx*my + G11*my*my) - Lmax;

    float* o = gcoef + (j >> 1) * 12 + (j & 1);
    o[0]  = c0;
    o[2]  = c1;
    o[4]  = c2;
    o[6]  = -G00;
    o[8]  = -G2;
    o[10] = -G11;
    if (j == 0) outLmax[0] = Lmax;
}

// ---------------------------------------------------------------------------
// Main kernel: 64 samples per block-partition, 4 wave-partitions per block
// (part = tid>>6 covers component pairs [part*128, part*128+128)).
// Coefficients are wave-uniform -> readfirstlane forces scalar (s_load) path.
// Packed-f32 math: 5 v_pk_fma per 2 components.
// ---------------------------------------------------------------------------
__global__ __launch_bounds__(256) void gm_main(
        const float* __restrict__ sample,   // [N,2]
        const float* __restrict__ gcoef,    // [512][6][2]
        const float* __restrict__ gLmax,
        float* __restrict__ out) {          // [N,1]
    __shared__ float SRED[256];

    const int tid   = threadIdx.x;
    const int slane = tid & 63;
    const int part  = __builtin_amdgcn_readfirstlane(tid >> 6);  // wave-uniform
    const int i     = blockIdx.x * 64 + slane;

    const float2 xy = ((const float2*)sample)[i];
    const float x = xy.x, y = xy.y;
    const v2f X  = {x, y ? x : x};  // avoid over-clever init; see below
    const v2f Xv = {x, x}, Yv = {y, y};
    const v2f X2 = {x*x, x*x}, XY = {x*y, x*y}, Y2 = {y*y, y*y};
    (void)X;

    const v2f* cp = (const v2f*)gcoef + part * 768;   // 128 pairs * 6 v2f

    float s0 = 0.f, s1 = 0.f, s2 = 0.f, s3 = 0.f;

    for (int p = 0; p < 128; p += 2) {
        const v2f* q = cp + p * 6;
        v2f a0 = q[0], a1 = q[1], a2 = q[2], a3 = q[3], a4 = q[4],  a5 = q[5];
        v2f b0 = q[6], b1 = q[7], b2 = q[8], b3 = q[9], b4 = q[10], b5 = q[11];

        v2f tA = __builtin_elementwise_fma(a1, Xv, a0);
        tA = __builtin_elementwise_fma(a2, Yv, tA);
        tA = __builtin_elementwise_fma(a3, X2, tA);
        tA = __builtin_elementwise_fma(a4, XY, tA);
        tA = __builtin_elementwise_fma(a5, Y2, tA);

        v2f tB = __builtin_elementwise_fma(b1, Xv, b0);
        tB = __builtin_elementwise_fma(b2, Yv, tB);
        tB = __builtin_elementwise_fma(b3, X2, tB);
        tB = __builtin_elementwise_fma(b4, XY, tB);
        tB = __builtin_elementwise_fma(b5, Y2, tB);

        s0 += fast_exp2(tA.x); s1 += fast_exp2(tA.y);
        s2 += fast_exp2(tB.x); s3 += fast_exp2(tB.y);
    }

    SRED[tid] = (s0 + s1) + (s2 + s3);
    __syncthreads();

    if (tid < 64) {
        const float Lmax = gLmax[0];
        float st = SRED[tid] + SRED[tid+64] + SRED[tid+128] + SRED[tid+192];
        float ll;
        if (st >= 1e-30f) {
            ll = LN2 * (Lmax + log2f(st));
        } else {
            // Rare underflow path: two-pass re-anchored logsumexp over all M.
            const v2f* fc = (const v2f*)gcoef;
            float m = -3e38f;
            for (int p = 0; p < 512; p++) {
                const v2f* q = fc + p * 6;
                v2f t = __builtin_elementwise_fma(q[1], Xv, q[0]);
                t = __builtin_elementwise_fma(q[2], Yv, t);
                t = __builtin_elementwise_fma(q[3], X2, t);
                t = __builtin_elementwise_fma(q[4], XY, t);
                t = __builtin_elementwise_fma(q[5], Y2, t);
                m = fmaxf(m, fmaxf(t.x, t.y));
            }
            float ss = 0.f;
            for (int p = 0; p < 512; p++) {
                const v2f* q = fc + p * 6;
                v2f t = __builtin_elementwise_fma(q[1], Xv, q[0]);
                t = __builtin_elementwise_fma(q[2], Yv, t);
                t = __builtin_elementwise_fma(q[3], X2, t);
                t = __builtin_elementwise_fma(q[4], XY, t);
                t = __builtin_elementwise_fma(q[5], Y2, t);
                ss += fast_exp2(t.x - m) + fast_exp2(t.y - m);
            }
            ll = LN2 * (Lmax + m + log2f(ss));
        }
        out[i] = ll;
    }
}

extern "C" void kernel_launch(void* const* d_in, const int* in_sizes, int n_in,
                              void* d_out, int out_size, void* d_ws, size_t ws_size,
                              hipStream_t stream) {
    const float* sample = (const float*)d_in[0];   // [N,2]
    const float* mu     = (const float*)d_in[1];   // [M,2]
    const float* A      = (const float*)d_in[2];   // [M,2,2]
    const float* w      = (const float*)d_in[3];   // [M,1]
    float* out = (float*)d_out;

    const int N = in_sizes[0] / 2;                 // 65536
    // M fixed at 1024 by the problem (coefficient layout sized statically).

    float* gcoef = (float*)d_ws;                          // 1024*6*4 = 24576 B
    float* lmax  = (float*)((char*)d_ws + 24576);         // 4 B

    gm_prep<<<1, 1024, 0, stream>>>(mu, A, w, gcoef, lmax);
    gm_main<<<N / 64, 256, 0, stream>>>(sample, gcoef, lmax, out);
}

// Round 3
// 21.640 us; speedup vs baseline: 1.2602x; 1.1908x over previous
//
#include <hip/hip_runtime.h>
#include <hip/hip_bf16.h>
#include <math.h>

#define LOG2E 1.4426950408889634f
#define LN2   0.6931471805599453f

typedef float v2f __attribute__((ext_vector_type(2)));

__device__ __forceinline__ float fast_exp2(float x) {
#if __has_builtin(__builtin_amdgcn_exp2f)
    return __builtin_amdgcn_exp2f(x);
#else
    return exp2f(x);
#endif
}

// ---------------------------------------------------------------------------
// Single fused kernel. Each block handles 64 samples and redundantly
// recomputes the per-component coefficient prep for all M=1024 components
// (prep ~ 0.5 us of VALU; saves a dependent kernel launch ~10 us).
//
// Coefficients, log2 domain, anchored at Lmax so t <= 0:
//   t_ij = c0 + c1*x + c2*y + d0*x^2 + d1*xy + d2*y^2
// LDS layout: pair p (components 2p, 2p+1) -> 3 float4:
//   f0 = (c0,c0', c1,c1')   f1 = (c2,c2', d0,d0')   f2 = (d1,d1', d2,d2')
// ---------------------------------------------------------------------------
__global__ __launch_bounds__(256) void gm_fused(
        const float* __restrict__ sample,   // [N,2]
        const float* __restrict__ mu,       // [M,2]
        const float* __restrict__ A,        // [M,2,2]
        const float* __restrict__ w,        // [M,1]
        float* __restrict__ out) {          // [N,1]
    __shared__ float4 COEF4[1536];          // 24 KB
    __shared__ float RED4[4];
    __shared__ float SRED[256];

    const int tid  = threadIdx.x;
    const int lane = tid & 63;
    const int wid  = tid >> 6;

    // ---- sample features (all 4 waves load the same 64 samples) ----
    const int i = blockIdx.x * 64 + lane;
    const float2 xy = ((const float2*)sample)[i];
    const float x = xy.x, y = xy.y;
    const v2f Xv = {x, x}, Yv = {y, y};
    const v2f X2 = {x*x, x*x}, XY = {x*y, x*y}, Y2 = {y*y, y*y};

    // ================= Phase 1: coefficient prep (per block) ==============
    // Thread t owns components 4t..4t+3 (= coefficient pairs 2t, 2t+1).
    const float4 wv = ((const float4*)w)[tid];
    const float wj[4] = {wv.x, wv.y, wv.z, wv.w};

    // block max of w
    float v = fmaxf(fmaxf(wv.x, wv.y), fmaxf(wv.z, wv.w));
    #pragma unroll
    for (int o = 32; o; o >>= 1) v = fmaxf(v, __shfl_xor(v, o));
    if (lane == 0) RED4[wid] = v;
    __syncthreads();
    const float wmax = fmaxf(fmaxf(RED4[0], RED4[1]), fmaxf(RED4[2], RED4[3]));
    __syncthreads();

    // block sum of exp(w - wmax)  ->  lse
    v = expf(wv.x - wmax) + expf(wv.y - wmax) + expf(wv.z - wmax) + expf(wv.w - wmax);
    #pragma unroll
    for (int o = 32; o; o >>= 1) v += __shfl_xor(v, o);
    if (lane == 0) RED4[wid] = v;
    __syncthreads();
    const float lse = wmax + logf(RED4[0] + RED4[1] + RED4[2] + RED4[3]);
    __syncthreads();

    // per-component gamma & log-weight (log2 domain)
    float lw2[4], G00[4], G2[4], G11[4], MX[4], MY[4];
    #pragma unroll
    for (int k = 0; k < 4; k++) {
        const int j = 4 * tid + k;
        const float4 a = ((const float4*)A)[j];
        const float g00 = 0.5f * (a.x*a.x + a.y*a.y);
        const float g01 = 0.5f * (a.x*a.z + a.y*a.w);
        const float g11 = 0.5f * (a.z*a.z + a.w*a.w);
        const float det = g00*g11 - g01*g01;
        lw2[k] = ((wj[k] - lse) + 0.5f * logf(det)) * LOG2E;
        G00[k] = g00 * LOG2E;
        G2[k]  = 2.f * g01 * LOG2E;
        G11[k] = g11 * LOG2E;
        const float2 m = ((const float2*)mu)[j];
        MX[k] = m.x; MY[k] = m.y;
    }

    // Lmax = max_j lw2_j
    v = fmaxf(fmaxf(lw2[0], lw2[1]), fmaxf(lw2[2], lw2[3]));
    #pragma unroll
    for (int o = 32; o; o >>= 1) v = fmaxf(v, __shfl_xor(v, o));
    if (lane == 0) RED4[wid] = v;
    __syncthreads();
    const float Lmax = fmaxf(fmaxf(RED4[0], RED4[1]), fmaxf(RED4[2], RED4[3]));

    // pack + store coefficient pairs (3 x ds_write_b128 per pair)
    #pragma unroll
    for (int kk = 0; kk < 2; kk++) {
        const int k0 = 2*kk, k1 = 2*kk + 1;
        float c0[2], c1[2], c2[2];
        #pragma unroll
        for (int h = 0; h < 2; h++) {
            const int k = k0 + h;
            c1[h] = 2.f*G00[k]*MX[k] + G2[k]*MY[k];
            c2[h] = G2[k]*MX[k] + 2.f*G11[k]*MY[k];
            c0[h] = lw2[k] - (G00[k]*MX[k]*MX[k] + G2[k]*MX[k]*MY[k]
                              + G11[k]*MY[k]*MY[k]) - Lmax;
        }
        const int p = 2 * tid + kk;
        COEF4[3*p + 0] = make_float4(c0[0], c0[1], c1[0], c1[1]);
        COEF4[3*p + 1] = make_float4(c2[0], c2[1], -G00[k0], -G00[k1]);
        COEF4[3*p + 2] = make_float4(-G2[k0], -G2[k1], -G11[k0], -G11[k1]);
    }
    __syncthreads();

    // ================= Phase 2: hot loop (256 comps per thread) ===========
    const int part = __builtin_amdgcn_readfirstlane(wid);   // wave-uniform
    const float4* cp = COEF4 + part * 384;                  // 128 pairs * 3

    float s0 = 0.f, s1 = 0.f, s2 = 0.f, s3 = 0.f;

    for (int p = 0; p < 128; p += 2) {
        const float4 f0 = cp[0], f1 = cp[1], f2 = cp[2];
        const float4 f3 = cp[3], f4 = cp[4], f5 = cp[5];
        cp += 6;

        v2f tA = __builtin_elementwise_fma((v2f){f0.z, f0.w}, Xv, (v2f){f0.x, f0.y});
        tA = __builtin_elementwise_fma((v2f){f1.x, f1.y}, Yv, tA);
        tA = __builtin_elementwise_fma((v2f){f1.z, f1.w}, X2, tA);
        tA = __builtin_elementwise_fma((v2f){f2.x, f2.y}, XY, tA);
        tA = __builtin_elementwise_fma((v2f){f2.z, f2.w}, Y2, tA);

        v2f tB = __builtin_elementwise_fma((v2f){f3.z, f3.w}, Xv, (v2f){f3.x, f3.y});
        tB = __builtin_elementwise_fma((v2f){f4.x, f4.y}, Yv, tB);
        tB = __builtin_elementwise_fma((v2f){f4.z, f4.w}, X2, tB);
        tB = __builtin_elementwise_fma((v2f){f5.x, f5.y}, XY, tB);
        tB = __builtin_elementwise_fma((v2f){f5.z, f5.w}, Y2, tB);

        s0 += fast_exp2(tA.x); s1 += fast_exp2(tA.y);
        s2 += fast_exp2(tB.x); s3 += fast_exp2(tB.y);
    }

    SRED[tid] = (s0 + s1) + (s2 + s3);
    __syncthreads();

    // ================= Phase 3: combine parts, logsumexp ==================
    if (tid < 64) {
        float st = SRED[tid] + SRED[tid+64] + SRED[tid+128] + SRED[tid+192];
        float ll;
        if (st >= 1e-30f) {
            ll = LN2 * (Lmax + log2f(st));
        } else {
            // Rare underflow: two-pass re-anchored logsumexp over all M.
            float m = -3e38f;
            for (int p = 0; p < 512; p++) {
                const float4 f0 = COEF4[3*p], f1 = COEF4[3*p+1], f2 = COEF4[3*p+2];
                v2f t = __builtin_elementwise_fma((v2f){f0.z, f0.w}, Xv, (v2f){f0.x, f0.y});
                t = __builtin_elementwise_fma((v2f){f1.x, f1.y}, Yv, t);
                t = __builtin_elementwise_fma((v2f){f1.z, f1.w}, X2, t);
                t = __builtin_elementwise_fma((v2f){f2.x, f2.y}, XY, t);
                t = __builtin_elementwise_fma((v2f){f2.z, f2.w}, Y2, t);
                m = fmaxf(m, fmaxf(t.x, t.y));
            }
            float ss = 0.f;
            for (int p = 0; p < 512; p++) {
                const float4 f0 = COEF4[3*p], f1 = COEF4[3*p+1], f2 = COEF4[3*p+2];
                v2f t = __builtin_elementwise_fma((v2f){f0.z, f0.w}, Xv, (v2f){f0.x, f0.y});
                t = __builtin_elementwise_fma((v2f){f1.x, f1.y}, Yv, t);
                t = __builtin_elementwise_fma((v2f){f1.z, f1.w}, X2, t);
                t = __builtin_elementwise_fma((v2f){f2.x, f2.y}, XY, t);
                t = __builtin_elementwise_fma((v2f){f2.z, f2.w}, Y2, t);
                ss += fast_exp2(t.x - m) + fast_exp2(t.y - m);
            }
            ll = LN2 * (Lmax + m + log2f(ss));
        }
        out[i] = ll;
    }
}

extern "C" void kernel_launch(void* const* d_in, const int* in_sizes, int n_in,
                              void* d_out, int out_size, void* d_ws, size_t ws_size,
                              hipStream_t stream) {
    const float* sample = (const float*)d_in[0];   // [N,2]
    const float* mu     = (const float*)d_in[1];   // [M,2]
    const float* A      = (const float*)d_in[2];   // [M,2,2]
    const float* w      = (const float*)d_in[3];   // [M,1]
    float* out = (float*)d_out;

    const int N = in_sizes[0] / 2;                 // 65536
    // M fixed at 1024 (LDS layout + per-thread prep sized statically).

    gm_fused<<<N / 64, 256, 0, stream>>>(sample, mu, A, w, out);
}